// Round 2
// baseline (374.726 us; speedup 1.0000x reference)
//
#include <hip/hip_runtime.h>
#include <hip/hip_bf16.h>

// StandardAttention: B=2, N=4096, D=512, H=8, HD=64, causal.
// R2: balanced paired q-tiles, barrier-free attn (K/V frags direct from global),
//     softmax scale folded into Q (log2 domain), coalesced weight transpose.

typedef __bf16 bf16_t;
typedef __bf16 bf16x4 __attribute__((ext_vector_type(4)));
typedef __bf16 bf16x8 __attribute__((ext_vector_type(8)));
typedef float  f32x4  __attribute__((ext_vector_type(4)));

// ---------------- conversion kernels ----------------

__global__ void convert_f32_bf16(const float* __restrict__ in, bf16_t* __restrict__ out) {
    int i = blockIdx.x * 256 + threadIdx.x;       // one float4 per thread, exact grid
    float4 v = ((const float4*)in)[i];
    bf16x4 o;
    o[0] = (bf16_t)v.x; o[1] = (bf16_t)v.y; o[2] = (bf16_t)v.z; o[3] = (bf16_t)v.w;
    ((bf16x4*)out)[i] = o;
}

// in: [512][N] fp32 row-major -> out: [N][512] bf16. Coalesced reads; scattered
// writes stay in L2 (out <= 1.5 MB).
__global__ void transpose_convert(const float* __restrict__ in, bf16_t* __restrict__ out, int N) {
    int n = blockIdx.x * 256 + threadIdx.x;
    int k = blockIdx.y;
    out[(size_t)n * 512 + k] = (bf16_t)in[(size_t)k * N + n];
}

// ---------------- GEMM: C[M,Ncols] = A[M,512] * Bt[Ncols,512]^T + bias ----------------
// MODE 0: QKV projection -> Q (pre-scaled by 0.125*log2e) [BH][4096][64],
//         K [BH][4096][64], Vt [BH][64][4096] (bf16)
// MODE 1: out projection -> Cout fp32 [M,512]

template <int MODE>
__global__ __launch_bounds__(256) void gemm_bt(
    const bf16_t* __restrict__ A, const bf16_t* __restrict__ Bt,
    const float* __restrict__ bias,
    bf16_t* __restrict__ Qg, bf16_t* __restrict__ Kg, bf16_t* __restrict__ Vt,
    float* __restrict__ Cout)
{
    __shared__ bf16_t As[128][72];   // +8 pad: breaks 16-way ds_read_b128 bank conflict
    __shared__ bf16_t Bs[128][72];
    const int tid  = threadIdx.x;
    const int wid  = tid >> 6, lane = tid & 63, l16 = lane & 15, quad = lane >> 4;
    const int wr   = (wid >> 1) * 64, wc = (wid & 1) * 64;
    const int m0   = blockIdx.y * 128, n0 = blockIdx.x * 128;

    f32x4 acc[4][4] = {};

    for (int kk = 0; kk < 512; kk += 64) {
        __syncthreads();
        #pragma unroll
        for (int i = 0; i < 4; ++i) {
            int c = tid + i * 256, row = c >> 3, col8 = (c & 7) * 8;
            *(uint4*)&As[row][col8] = *(const uint4*)(A  + (size_t)(m0 + row) * 512 + kk + col8);
            *(uint4*)&Bs[row][col8] = *(const uint4*)(Bt + (size_t)(n0 + row) * 512 + kk + col8);
        }
        __syncthreads();
        #pragma unroll
        for (int s = 0; s < 2; ++s) {
            bf16x8 a[4], b[4];
            #pragma unroll
            for (int i = 0; i < 4; ++i) a[i] = *(const bf16x8*)&As[wr + i * 16 + l16][s * 32 + quad * 8];
            #pragma unroll
            for (int j = 0; j < 4; ++j) b[j] = *(const bf16x8*)&Bs[wc + j * 16 + l16][s * 32 + quad * 8];
            #pragma unroll
            for (int i = 0; i < 4; ++i)
                #pragma unroll
                for (int j = 0; j < 4; ++j)
                    acc[i][j] = __builtin_amdgcn_mfma_f32_16x16x32_bf16(a[i], b[j], acc[i][j], 0, 0, 0);
        }
    }

    // epilogue: C/D layout col=lane&15, row=quad*4+reg
    const float qscale = 0.18033688011112042f;   // 0.125 * log2(e), folded into Q
    #pragma unroll
    for (int i = 0; i < 4; ++i) {
        int mrow = m0 + wr + i * 16 + quad * 4;
        #pragma unroll
        for (int j = 0; j < 4; ++j) {
            int cgl = n0 + wc + j * 16 + l16;
            float bv = bias[cgl];
            #pragma unroll
            for (int r = 0; r < 4; ++r) {
                int m = mrow + r;
                float val = acc[i][j][r] + bv;
                if (MODE == 0) {
                    int which = cgl >> 9, hh = (cgl >> 6) & 7, hd = cgl & 63;
                    int b_ = m >> 12, n = m & 4095, bh = b_ * 8 + hh;
                    if (which == 0)      Qg[((size_t)bh * 4096 + n) * 64 + hd] = (bf16_t)(val * qscale);
                    else if (which == 1) Kg[((size_t)bh * 4096 + n) * 64 + hd] = (bf16_t)val;
                    else                 Vt[((size_t)bh * 64 + hd) * 4096 + n] = (bf16_t)val;
                } else {
                    Cout[(size_t)m * 512 + cgl] = val;
                }
            }
        }
    }
}

// ---------------- flash attention ----------------
// grid = 16 bh * 32 pairs; block = 256 (4 waves, each wave owns a 16-row q stripe).
// Block processes q-tiles pr and 63-pr sequentially -> uniform 65 k-tile iters.
// Barrier-free: K/V fragments loaded directly from global (L1/L2-served);
// LDS only for the per-wave P C-layout -> A-layout round-trip.

__global__ __launch_bounds__(256) void attn_kernel(
    const bf16_t* __restrict__ Qg, const bf16_t* __restrict__ Kg,
    const bf16_t* __restrict__ Vt, bf16_t* __restrict__ Og)
{
    __shared__ bf16_t Ps[4][16][72];     // per-wave private

    const int tid  = threadIdx.x;
    const int w    = tid >> 6, lane = tid & 63, l16 = lane & 15, quad = lane >> 4;
    const int bh   = blockIdx.x >> 5, pr = blockIdx.x & 31;
    const int b_   = bh >> 3, hh = bh & 7;

    #pragma unroll
    for (int half = 0; half < 2; ++half) {
        const int qt = half ? (63 - pr) : pr;

        const int qrow = qt * 64 + w * 16 + l16;
        const bf16_t* qp = Qg + ((size_t)bh * 4096 + qrow) * 64;
        bf16x8 qf0 = *(const bf16x8*)(qp + quad * 8);
        bf16x8 qf1 = *(const bf16x8*)(qp + 32 + quad * 8);

        f32x4 o[4] = {};
        float mrun[4], lrun[4];
        #pragma unroll
        for (int r = 0; r < 4; ++r) { mrun[r] = -1e30f; lrun[r] = 0.f; }

        for (int kt = 0; kt <= qt; ++kt) {
            // K/V fragments straight from global: all 4 waves read the same
            // 16 KB -> L1 hits; no LDS staging, no barriers.
            const bf16_t* kbase = Kg + ((size_t)(bh * 4096 + kt * 64)) * 64;
            const bf16_t* vbase = Vt + (size_t)bh * 64 * 4096 + kt * 64;
            bf16x8 kf[4][2], vf[4][2];
            #pragma unroll
            for (int cb = 0; cb < 4; ++cb) {
                const bf16_t* kp = kbase + (cb * 16 + l16) * 64 + quad * 8;
                kf[cb][0] = *(const bf16x8*)kp;
                kf[cb][1] = *(const bf16x8*)(kp + 32);
            }
            #pragma unroll
            for (int j = 0; j < 4; ++j) {
                const bf16_t* vp = vbase + (size_t)(j * 16 + l16) * 4096 + quad * 8;
                vf[j][0] = *(const bf16x8*)vp;
                vf[j][1] = *(const bf16x8*)(vp + 32);
            }

            // S stripe: 16 q rows x 64 keys (already in log2 domain via Q pre-scale)
            f32x4 s[4] = {};
            #pragma unroll
            for (int cb = 0; cb < 4; ++cb) {
                s[cb] = __builtin_amdgcn_mfma_f32_16x16x32_bf16(qf0, kf[cb][0], s[cb], 0, 0, 0);
                s[cb] = __builtin_amdgcn_mfma_f32_16x16x32_bf16(qf1, kf[cb][1], s[cb], 0, 0, 0);
            }

            if (kt == qt) {              // causal mask, diagonal tile only
                const int qq = w * 16 + quad * 4;
                #pragma unroll
                for (int cb = 0; cb < 4; ++cb) {
                    const int key = cb * 16 + l16;
                    #pragma unroll
                    for (int r = 0; r < 4; ++r)
                        if (key > qq + r) s[cb][r] = -1e30f;
                }
            }

            // online softmax, log2 domain (rows live on 16-lane groups)
            float alpha[4];
            #pragma unroll
            for (int r = 0; r < 4; ++r) {
                float v = fmaxf(fmaxf(s[0][r], s[1][r]), fmaxf(s[2][r], s[3][r]));
                v = fmaxf(v, __shfl_xor(v, 1));
                v = fmaxf(v, __shfl_xor(v, 2));
                v = fmaxf(v, __shfl_xor(v, 4));
                v = fmaxf(v, __shfl_xor(v, 8));
                float mn = fmaxf(mrun[r], v);
                alpha[r] = exp2f(mrun[r] - mn);
                mrun[r] = mn;
            }
            float ls[4] = {0.f, 0.f, 0.f, 0.f};
            #pragma unroll
            for (int cb = 0; cb < 4; ++cb)
                #pragma unroll
                for (int r = 0; r < 4; ++r) {
                    float p = exp2f(s[cb][r] - mrun[r]);
                    s[cb][r] = p;
                    ls[r] += p;
                }
            #pragma unroll
            for (int r = 0; r < 4; ++r) {
                float v = ls[r];
                v += __shfl_xor(v, 1);
                v += __shfl_xor(v, 2);
                v += __shfl_xor(v, 4);
                v += __shfl_xor(v, 8);
                lrun[r] = lrun[r] * alpha[r] + v;
            }
            #pragma unroll
            for (int j = 0; j < 4; ++j)
                #pragma unroll
                for (int r = 0; r < 4; ++r) o[j][r] *= alpha[r];

            // P: C-layout -> LDS -> A-layout (per-wave region; DS in-order per wave)
            #pragma unroll
            for (int cb = 0; cb < 4; ++cb)
                #pragma unroll
                for (int r = 0; r < 4; ++r)
                    Ps[w][quad * 4 + r][cb * 16 + l16] = (bf16_t)s[cb][r];
            bf16x8 pa0 = *(const bf16x8*)&Ps[w][l16][quad * 8];
            bf16x8 pa1 = *(const bf16x8*)&Ps[w][l16][32 + quad * 8];

            #pragma unroll
            for (int j = 0; j < 4; ++j) {
                o[j] = __builtin_amdgcn_mfma_f32_16x16x32_bf16(pa0, vf[j][0], o[j], 0, 0, 0);
                o[j] = __builtin_amdgcn_mfma_f32_16x16x32_bf16(pa1, vf[j][1], o[j], 0, 0, 0);
            }
        }

        // write O as [B][N][H*64] bf16 for the out-projection GEMM
        #pragma unroll
        for (int r = 0; r < 4; ++r) {
            float inv = 1.f / lrun[r];
            int n = qt * 64 + w * 16 + quad * 4 + r;
            #pragma unroll
            for (int j = 0; j < 4; ++j)
                Og[((size_t)(b_ * 4096 + n)) * 512 + hh * 64 + j * 16 + l16] =
                    (bf16_t)(o[j][r] * inv);
        }
    }
}

// ---------------- launch ----------------

extern "C" void kernel_launch(void* const* d_in, const int* in_sizes, int n_in,
                              void* d_out, int out_size, void* d_ws, size_t ws_size,
                              hipStream_t stream) {
    const float* x    = (const float*)d_in[0];   // [2,4096,512]
    const float* Wqkv = (const float*)d_in[1];   // [512,1536]
    const float* bqkv = (const float*)d_in[2];   // [1536]
    const float* Wout = (const float*)d_in[3];   // [512,512]
    const float* bout = (const float*)d_in[4];   // [512]
    float* out = (float*)d_out;                  // [2,4096,512] fp32

    char* ws = (char*)d_ws;
    bf16_t* xb  = (bf16_t*)(ws);                 // 8 MB (reused as Og after QKV GEMM)
    bf16_t* WqT = (bf16_t*)(ws + 8388608);       // 1.5 MB
    bf16_t* WoT = (bf16_t*)(ws + 9961472);       // 0.5 MB
    bf16_t* Qg  = (bf16_t*)(ws + 10485760);      // 8 MB (pre-scaled by 0.125*log2e)
    bf16_t* Kg  = (bf16_t*)(ws + 18874368);      // 8 MB
    bf16_t* Vt  = (bf16_t*)(ws + 27262976);      // 8 MB ([bh][64][4096])

    convert_f32_bf16<<<4096, 256, 0, stream>>>(x, xb);
    transpose_convert<<<dim3(6, 512), 256, 0, stream>>>(Wqkv, WqT, 1536);
    transpose_convert<<<dim3(2, 512), 256, 0, stream>>>(Wout, WoT, 512);

    gemm_bt<0><<<dim3(12, 64), 256, 0, stream>>>(xb, WqT, bqkv, Qg, Kg, Vt, nullptr);

    attn_kernel<<<512, 256, 0, stream>>>(Qg, Kg, Vt, xb /* Og */);

    gemm_bt<1><<<dim3(4, 64), 256, 0, stream>>>(xb, WoT, bout, nullptr, nullptr, nullptr, out);
}

// Round 3
// 363.368 us; speedup vs baseline: 1.0313x; 1.0313x over previous
//
#include <hip/hip_runtime.h>
#include <hip/hip_bf16.h>

// StandardAttention: B=2, N=4096, D=512, H=8, HD=64, causal.
// R3: attn rebuilt — 256 blocks (guaranteed CU-level balance via intra-block
// supertile pairing), 4 waves x 2 stripes (K/V frag reuse), double-buffered
// LDS staging, V transposed during staging with XOR swizzle.

typedef __bf16 bf16_t;
typedef __bf16 bf16x4 __attribute__((ext_vector_type(4)));
typedef __bf16 bf16x8 __attribute__((ext_vector_type(8)));
typedef float  f32x4  __attribute__((ext_vector_type(4)));

// ---------------- conversion kernels ----------------

__global__ void convert_f32_bf16(const float* __restrict__ in, bf16_t* __restrict__ out) {
    int i = blockIdx.x * 256 + threadIdx.x;
    float4 v = ((const float4*)in)[i];
    bf16x4 o;
    o[0] = (bf16_t)v.x; o[1] = (bf16_t)v.y; o[2] = (bf16_t)v.z; o[3] = (bf16_t)v.w;
    ((bf16x4*)out)[i] = o;
}

// in: [512][N] fp32 -> out: [N][512] bf16 (coalesced reads, L2-held writes)
__global__ void transpose_convert(const float* __restrict__ in, bf16_t* __restrict__ out, int N) {
    int n = blockIdx.x * 256 + threadIdx.x;
    int k = blockIdx.y;
    out[(size_t)n * 512 + k] = (bf16_t)in[(size_t)k * N + n];
}

// ---------------- GEMM: C[M,Ncols] = A[M,512] * Bt[Ncols,512]^T + bias ----------------
// MODE 0: QKV -> Q (pre-scaled 0.125*log2e), K, V, all [BH][4096][64] bf16
// MODE 1: out projection -> Cout fp32 [M,512]

template <int MODE>
__global__ __launch_bounds__(256) void gemm_bt(
    const bf16_t* __restrict__ A, const bf16_t* __restrict__ Bt,
    const float* __restrict__ bias,
    bf16_t* __restrict__ Qg, bf16_t* __restrict__ Kg, bf16_t* __restrict__ Vg,
    float* __restrict__ Cout)
{
    __shared__ bf16_t As[128][72];
    __shared__ bf16_t Bs[128][72];
    const int tid  = threadIdx.x;
    const int wid  = tid >> 6, lane = tid & 63, l16 = lane & 15, quad = lane >> 4;
    const int wr   = (wid >> 1) * 64, wc = (wid & 1) * 64;
    const int m0   = blockIdx.y * 128, n0 = blockIdx.x * 128;

    f32x4 acc[4][4] = {};

    for (int kk = 0; kk < 512; kk += 64) {
        __syncthreads();
        #pragma unroll
        for (int i = 0; i < 4; ++i) {
            int c = tid + i * 256, row = c >> 3, col8 = (c & 7) * 8;
            *(uint4*)&As[row][col8] = *(const uint4*)(A  + (size_t)(m0 + row) * 512 + kk + col8);
            *(uint4*)&Bs[row][col8] = *(const uint4*)(Bt + (size_t)(n0 + row) * 512 + kk + col8);
        }
        __syncthreads();
        #pragma unroll
        for (int s = 0; s < 2; ++s) {
            bf16x8 a[4], b[4];
            #pragma unroll
            for (int i = 0; i < 4; ++i) a[i] = *(const bf16x8*)&As[wr + i * 16 + l16][s * 32 + quad * 8];
            #pragma unroll
            for (int j = 0; j < 4; ++j) b[j] = *(const bf16x8*)&Bs[wc + j * 16 + l16][s * 32 + quad * 8];
            #pragma unroll
            for (int i = 0; i < 4; ++i)
                #pragma unroll
                for (int j = 0; j < 4; ++j)
                    acc[i][j] = __builtin_amdgcn_mfma_f32_16x16x32_bf16(a[i], b[j], acc[i][j], 0, 0, 0);
        }
    }

    const float qscale = 0.18033688011112042f;   // 0.125 * log2(e)
    #pragma unroll
    for (int i = 0; i < 4; ++i) {
        int mrow = m0 + wr + i * 16 + quad * 4;
        #pragma unroll
        for (int j = 0; j < 4; ++j) {
            int cgl = n0 + wc + j * 16 + l16;
            float bv = bias[cgl];
            #pragma unroll
            for (int r = 0; r < 4; ++r) {
                int m = mrow + r;
                float val = acc[i][j][r] + bv;
                if (MODE == 0) {
                    int which = cgl >> 9, hh = (cgl >> 6) & 7, hd = cgl & 63;
                    int b_ = m >> 12, n = m & 4095, bh = b_ * 8 + hh;
                    size_t idx = ((size_t)bh * 4096 + n) * 64 + hd;
                    if (which == 0)      Qg[idx] = (bf16_t)(val * qscale);
                    else if (which == 1) Kg[idx] = (bf16_t)val;
                    else                 Vg[idx] = (bf16_t)val;
                } else {
                    Cout[(size_t)m * 512 + cgl] = val;
                }
            }
        }
    }
}

// ---------------- flash attention ----------------
// 256 blocks = 16 bh x 16 pair-indices. Block handles supertiles st=p and 31-p
// sequentially (128 q-rows each) -> uniform 68 k-tile iterations.
// 4 waves x 2 stripes of 16 q-rows (stripe s at q-offset s*64 + w*16).
// Double-buffered K/V LDS tiles; V transposed during staging (XOR swizzle).

__global__ __launch_bounds__(256, 1) void attn_kernel(
    const bf16_t* __restrict__ Qg, const bf16_t* __restrict__ Kg,
    const bf16_t* __restrict__ Vg, bf16_t* __restrict__ Og)
{
    __shared__ bf16_t Ks[2][64][72];     // [buf][key][hd], stride 72: conflict-free b128
    __shared__ bf16_t Vs[2][64][72];     // [buf][hd][key ^ (hd&56)], transposed + swizzled
    __shared__ bf16_t Ps[4][16][88];     // per-wave P round-trip; stride 88: 16B-aligned rows

    const int tid  = threadIdx.x;
    const int w    = tid >> 6, lane = tid & 63, l16 = lane & 15, quad = lane >> 4;
    const int bh   = blockIdx.x & 15, pidx = blockIdx.x >> 4;
    const int b_   = bh >> 3, hh = bh & 7;

    // staging indices (2 chunks of 256 threads each cover a 64x64 bf16 tile)
    const int key_c0 = tid >> 3,          hd0_c0 = (tid & 7) * 8;
    const int key_c1 = (tid + 256) >> 3,  hd0_c1 = (tid & 7) * 8;

    uint4 kr[2], vr[2];

    for (int ph = 0; ph < 2; ++ph) {
        const int st  = ph ? (31 - pidx) : pidx;
        const int nkt = 2 * st + 2;

        // Q fragments for both stripes (pre-scaled by 0.125*log2e)
        bf16x8 qf[2][2];
        #pragma unroll
        for (int s = 0; s < 2; ++s) {
            const bf16_t* qp = Qg + ((size_t)bh * 4096 + st * 128 + s * 64 + w * 16 + l16) * 64;
            qf[s][0] = *(const bf16x8*)(qp + quad * 8);
            qf[s][1] = *(const bf16x8*)(qp + 32 + quad * 8);
        }

        f32x4 o[2][4] = {};
        float mrun[2][4], lrun[2][4];
        #pragma unroll
        for (int s = 0; s < 2; ++s)
            #pragma unroll
            for (int r = 0; r < 4; ++r) { mrun[s][r] = -1e30f; lrun[s][r] = 0.f; }

        // ---- preload tile 0 ----
        {
            const size_t base = ((size_t)bh * 4096) * 64;
            kr[0] = *(const uint4*)(Kg + base + (size_t)key_c0 * 64 + hd0_c0);
            kr[1] = *(const uint4*)(Kg + base + (size_t)key_c1 * 64 + hd0_c1);
            vr[0] = *(const uint4*)(Vg + base + (size_t)key_c0 * 64 + hd0_c0);
            vr[1] = *(const uint4*)(Vg + base + (size_t)key_c1 * 64 + hd0_c1);
        }
        __syncthreads();   // previous phase's readers are done before we overwrite buf0
        {
            *(uint4*)&Ks[0][key_c0][hd0_c0] = kr[0];
            *(uint4*)&Ks[0][key_c1][hd0_c1] = kr[1];
            union { uint4 u; bf16_t h[8]; } uv;
            uv.u = vr[0];
            #pragma unroll
            for (int j = 0; j < 8; ++j) Vs[0][hd0_c0 + j][key_c0 ^ hd0_c0] = uv.h[j];
            uv.u = vr[1];
            #pragma unroll
            for (int j = 0; j < 8; ++j) Vs[0][hd0_c1 + j][key_c1 ^ hd0_c1] = uv.h[j];
        }

        for (int kt = 0; kt < nkt; ++kt) {
            const int  cur = kt & 1;
            const bool pre = (kt + 1 < nkt);
            if (pre) {   // issue next tile's global loads (no wait)
                const size_t base = ((size_t)bh * 4096 + (kt + 1) * 64) * 64;
                kr[0] = *(const uint4*)(Kg + base + (size_t)key_c0 * 64 + hd0_c0);
                kr[1] = *(const uint4*)(Kg + base + (size_t)key_c1 * 64 + hd0_c1);
                vr[0] = *(const uint4*)(Vg + base + (size_t)key_c0 * 64 + hd0_c0);
                vr[1] = *(const uint4*)(Vg + base + (size_t)key_c1 * 64 + hd0_c1);
            }
            __syncthreads();   // buf[cur] fully staged

            // K/V fragments, shared by both stripes
            bf16x8 kf[4][2], vf[4][2];
            #pragma unroll
            for (int cb = 0; cb < 4; ++cb) {
                kf[cb][0] = *(const bf16x8*)&Ks[cur][cb * 16 + l16][quad * 8];
                kf[cb][1] = *(const bf16x8*)&Ks[cur][cb * 16 + l16][32 + quad * 8];
            }
            #pragma unroll
            for (int j16 = 0; j16 < 4; ++j16) {
                const int hd = j16 * 16 + l16, hsw = hd & 56;
                vf[j16][0] = *(const bf16x8*)&Vs[cur][hd][(quad * 8) ^ hsw];
                vf[j16][1] = *(const bf16x8*)&Vs[cur][hd][(32 + quad * 8) ^ hsw];
            }

            #pragma unroll
            for (int s = 0; s < 2; ++s) {
                const int diag = 2 * st + s;
                if (kt > diag) continue;   // block-uniform: only s=0 at last kt

                f32x4 sv[4] = {};
                #pragma unroll
                for (int cb = 0; cb < 4; ++cb) {
                    sv[cb] = __builtin_amdgcn_mfma_f32_16x16x32_bf16(qf[s][0], kf[cb][0], sv[cb], 0, 0, 0);
                    sv[cb] = __builtin_amdgcn_mfma_f32_16x16x32_bf16(qf[s][1], kf[cb][1], sv[cb], 0, 0, 0);
                }

                if (kt == diag) {          // causal mask on the diagonal tile
                    const int qq = w * 16 + quad * 4;
                    #pragma unroll
                    for (int cb = 0; cb < 4; ++cb) {
                        const int key = cb * 16 + l16;
                        #pragma unroll
                        for (int r = 0; r < 4; ++r)
                            if (key > qq + r) sv[cb][r] = -1e30f;
                    }
                }

                // online softmax (log2 domain; rows on 16-lane groups)
                float alpha[4];
                #pragma unroll
                for (int r = 0; r < 4; ++r) {
                    float v = fmaxf(fmaxf(sv[0][r], sv[1][r]), fmaxf(sv[2][r], sv[3][r]));
                    v = fmaxf(v, __shfl_xor(v, 1));
                    v = fmaxf(v, __shfl_xor(v, 2));
                    v = fmaxf(v, __shfl_xor(v, 4));
                    v = fmaxf(v, __shfl_xor(v, 8));
                    float mn = fmaxf(mrun[s][r], v);
                    alpha[r] = exp2f(mrun[s][r] - mn);
                    mrun[s][r] = mn;
                }
                float ls[4] = {0.f, 0.f, 0.f, 0.f};
                #pragma unroll
                for (int cb = 0; cb < 4; ++cb)
                    #pragma unroll
                    for (int r = 0; r < 4; ++r) {
                        float p = exp2f(sv[cb][r] - mrun[s][r]);
                        sv[cb][r] = p;
                        ls[r] += p;
                    }
                #pragma unroll
                for (int r = 0; r < 4; ++r) {
                    float v = ls[r];
                    v += __shfl_xor(v, 1);
                    v += __shfl_xor(v, 2);
                    v += __shfl_xor(v, 4);
                    v += __shfl_xor(v, 8);
                    lrun[s][r] = lrun[s][r] * alpha[r] + v;
                }
                #pragma unroll
                for (int j = 0; j < 4; ++j)
                    #pragma unroll
                    for (int r = 0; r < 4; ++r) o[s][j][r] *= alpha[r];

                // P: C-layout -> LDS -> A-layout (per-wave region, in-wave DS order)
                #pragma unroll
                for (int cb = 0; cb < 4; ++cb)
                    #pragma unroll
                    for (int r = 0; r < 4; ++r)
                        Ps[w][quad * 4 + r][cb * 16 + l16] = (bf16_t)sv[cb][r];
                bf16x8 pa0 = *(const bf16x8*)&Ps[w][l16][quad * 8];
                bf16x8 pa1 = *(const bf16x8*)&Ps[w][l16][32 + quad * 8];

                #pragma unroll
                for (int j = 0; j < 4; ++j) {
                    o[s][j] = __builtin_amdgcn_mfma_f32_16x16x32_bf16(pa0, vf[j][0], o[s][j], 0, 0, 0);
                    o[s][j] = __builtin_amdgcn_mfma_f32_16x16x32_bf16(pa1, vf[j][1], o[s][j], 0, 0, 0);
                }
            }

            if (pre) {
                __syncthreads();   // all waves done reading buf[1-cur] (used at kt-1)
                const int nb = 1 - cur;
                *(uint4*)&Ks[nb][key_c0][hd0_c0] = kr[0];
                *(uint4*)&Ks[nb][key_c1][hd0_c1] = kr[1];
                union { uint4 u; bf16_t h[8]; } uv;
                uv.u = vr[0];
                #pragma unroll
                for (int j = 0; j < 8; ++j) Vs[nb][hd0_c0 + j][key_c0 ^ hd0_c0] = uv.h[j];
                uv.u = vr[1];
                #pragma unroll
                for (int j = 0; j < 8; ++j) Vs[nb][hd0_c1 + j][key_c1 ^ hd0_c1] = uv.h[j];
            }
        }

        // epilogue: O as [B][N][H*64] bf16
        #pragma unroll
        for (int s = 0; s < 2; ++s)
            #pragma unroll
            for (int r = 0; r < 4; ++r) {
                float inv = 1.f / lrun[s][r];
                int n = st * 128 + s * 64 + w * 16 + quad * 4 + r;
                #pragma unroll
                for (int j = 0; j < 4; ++j)
                    Og[((size_t)(b_ * 4096 + n)) * 512 + hh * 64 + j * 16 + l16] =
                        (bf16_t)(o[s][j][r] * inv);
            }
    }
}

// ---------------- launch ----------------

extern "C" void kernel_launch(void* const* d_in, const int* in_sizes, int n_in,
                              void* d_out, int out_size, void* d_ws, size_t ws_size,
                              hipStream_t stream) {
    const float* x    = (const float*)d_in[0];   // [2,4096,512]
    const float* Wqkv = (const float*)d_in[1];   // [512,1536]
    const float* bqkv = (const float*)d_in[2];   // [1536]
    const float* Wout = (const float*)d_in[3];   // [512,512]
    const float* bout = (const float*)d_in[4];   // [512]
    float* out = (float*)d_out;                  // [2,4096,512] fp32

    char* ws = (char*)d_ws;
    bf16_t* xb  = (bf16_t*)(ws);                 // 8 MB (reused as Og after QKV GEMM)
    bf16_t* WqT = (bf16_t*)(ws + 8388608);       // 1.5 MB
    bf16_t* WoT = (bf16_t*)(ws + 9961472);       // 0.5 MB
    bf16_t* Qg  = (bf16_t*)(ws + 10485760);      // 8 MB (pre-scaled)
    bf16_t* Kg  = (bf16_t*)(ws + 18874368);      // 8 MB
    bf16_t* Vg  = (bf16_t*)(ws + 27262976);      // 8 MB ([bh][n][64])

    convert_f32_bf16<<<4096, 256, 0, stream>>>(x, xb);
    transpose_convert<<<dim3(6, 512), 256, 0, stream>>>(Wqkv, WqT, 1536);
    transpose_convert<<<dim3(2, 512), 256, 0, stream>>>(Wout, WoT, 512);

    gemm_bt<0><<<dim3(12, 64), 256, 0, stream>>>(xb, WqT, bqkv, Qg, Kg, Vg, nullptr);

    attn_kernel<<<256, 256, 0, stream>>>(Qg, Kg, Vg, xb /* Og */);

    gemm_bt<1><<<dim3(4, 64), 256, 0, stream>>>(xb, WoT, bout, nullptr, nullptr, nullptr, out);
}

// Round 4
// 238.560 us; speedup vs baseline: 1.5708x; 1.5232x over previous
//
#include <hip/hip_runtime.h>
#include <hip/hip_bf16.h>

// StandardAttention: B=2, N=4096, D=512, H=8, HD=64, causal.
// R4: attn softmax chain rebuilt around S^T layout:
//  - S^T = K*Q^T  -> per-lane single-q softmax: 15 in-reg max + 2 shfls (was 8 shfls)
//  - row-sum l via ones-column MFMA (free on matrix pipe)
//  - P packed to bf16x4, 4 ds_write_b64 (was 16 b16 writes)
//  - 512 balanced blocks (paired q-tiles, 65 iters each) -> 2 blocks/CU, 2 waves/SIMD
//  - double-buffered K/V LDS, ONE barrier per k-tile, prefetch covered by compute

typedef __bf16 bf16_t;
typedef __bf16 bf16x4 __attribute__((ext_vector_type(4)));
typedef __bf16 bf16x8 __attribute__((ext_vector_type(8)));
typedef float  f32x4  __attribute__((ext_vector_type(4)));

// ---------------- conversion kernels ----------------

__global__ void convert_f32_bf16(const float* __restrict__ in, bf16_t* __restrict__ out) {
    int i = blockIdx.x * 256 + threadIdx.x;
    float4 v = ((const float4*)in)[i];
    bf16x4 o;
    o[0] = (bf16_t)v.x; o[1] = (bf16_t)v.y; o[2] = (bf16_t)v.z; o[3] = (bf16_t)v.w;
    ((bf16x4*)out)[i] = o;
}

// in: [512][N] fp32 -> out: [N][512] bf16 (coalesced reads, L2-held writes)
__global__ void transpose_convert(const float* __restrict__ in, bf16_t* __restrict__ out, int N) {
    int n = blockIdx.x * 256 + threadIdx.x;
    int k = blockIdx.y;
    out[(size_t)n * 512 + k] = (bf16_t)in[(size_t)k * N + n];
}

// ---------------- GEMM: C[M,Ncols] = A[M,512] * Bt[Ncols,512]^T + bias ----------------
// MODE 0: QKV -> Q (pre-scaled 0.125*log2e) [BH][4096][64], K [BH][4096][64],
//         Vt [BH][64][4096] (transposed V)
// MODE 1: out projection -> Cout fp32 [M,512]

template <int MODE>
__global__ __launch_bounds__(256) void gemm_bt(
    const bf16_t* __restrict__ A, const bf16_t* __restrict__ Bt,
    const float* __restrict__ bias,
    bf16_t* __restrict__ Qg, bf16_t* __restrict__ Kg, bf16_t* __restrict__ Vt,
    float* __restrict__ Cout)
{
    __shared__ bf16_t As[128][72];
    __shared__ bf16_t Bs[128][72];
    const int tid  = threadIdx.x;
    const int wid  = tid >> 6, lane = tid & 63, l16 = lane & 15, quad = lane >> 4;
    const int wr   = (wid >> 1) * 64, wc = (wid & 1) * 64;
    const int m0   = blockIdx.y * 128, n0 = blockIdx.x * 128;

    f32x4 acc[4][4] = {};

    for (int kk = 0; kk < 512; kk += 64) {
        __syncthreads();
        #pragma unroll
        for (int i = 0; i < 4; ++i) {
            int c = tid + i * 256, row = c >> 3, col8 = (c & 7) * 8;
            *(uint4*)&As[row][col8] = *(const uint4*)(A  + (size_t)(m0 + row) * 512 + kk + col8);
            *(uint4*)&Bs[row][col8] = *(const uint4*)(Bt + (size_t)(n0 + row) * 512 + kk + col8);
        }
        __syncthreads();
        #pragma unroll
        for (int s = 0; s < 2; ++s) {
            bf16x8 a[4], b[4];
            #pragma unroll
            for (int i = 0; i < 4; ++i) a[i] = *(const bf16x8*)&As[wr + i * 16 + l16][s * 32 + quad * 8];
            #pragma unroll
            for (int j = 0; j < 4; ++j) b[j] = *(const bf16x8*)&Bs[wc + j * 16 + l16][s * 32 + quad * 8];
            #pragma unroll
            for (int i = 0; i < 4; ++i)
                #pragma unroll
                for (int j = 0; j < 4; ++j)
                    acc[i][j] = __builtin_amdgcn_mfma_f32_16x16x32_bf16(a[i], b[j], acc[i][j], 0, 0, 0);
        }
    }

    const float qscale = 0.18033688011112042f;   // 0.125 * log2(e)
    #pragma unroll
    for (int i = 0; i < 4; ++i) {
        int mrow = m0 + wr + i * 16 + quad * 4;
        #pragma unroll
        for (int j = 0; j < 4; ++j) {
            int cgl = n0 + wc + j * 16 + l16;
            float bv = bias[cgl];
            #pragma unroll
            for (int r = 0; r < 4; ++r) {
                int m = mrow + r;
                float val = acc[i][j][r] + bv;
                if (MODE == 0) {
                    int which = cgl >> 9, hh = (cgl >> 6) & 7, hd = cgl & 63;
                    int b_ = m >> 12, n = m & 4095, bh = b_ * 8 + hh;
                    if (which == 0)      Qg[((size_t)bh * 4096 + n) * 64 + hd] = (bf16_t)(val * qscale);
                    else if (which == 1) Kg[((size_t)bh * 4096 + n) * 64 + hd] = (bf16_t)val;
                    else                 Vt[((size_t)bh * 64 + hd) * 4096 + n] = (bf16_t)val;
                } else {
                    Cout[(size_t)m * 512 + cgl] = val;
                }
            }
        }
    }
}

// ---------------- flash attention ----------------
// 512 blocks = 16 bh x 32 pair-indices; block runs q-tiles p and 63-p -> 65 iters.
// 4 waves, each owns a 16-q-row stripe. S^T softmax (see header).

__global__ __launch_bounds__(256) void attn_kernel(
    const bf16_t* __restrict__ Qg, const bf16_t* __restrict__ Kg,
    const bf16_t* __restrict__ Vt, bf16_t* __restrict__ Og)
{
    __shared__ bf16_t Ks[2][64][72];     // [buf][key][hd]
    __shared__ bf16_t Vs[2][64][72];     // [buf][hd][key]   (from pre-transposed Vt)
    __shared__ bf16_t Ps[4][16][72];     // per-wave P: [q][key]

    const int tid  = threadIdx.x;
    const int w    = tid >> 6, lane = tid & 63, l16 = lane & 15, quad = lane >> 4;
    const int bh   = blockIdx.x & 15, p = blockIdx.x >> 4;
    const int b_   = bh >> 3, hh = bh & 7;

    // staging chunks: c in {tid, tid+256}; row = c>>3, col8 = (c&7)*8
    const int row0 = tid >> 3,         col0 = (tid & 7) * 8;
    const int row1 = (tid + 256) >> 3, col1 = (tid & 7) * 8;

    bf16x8 ones;
    #pragma unroll
    for (int j = 0; j < 8; ++j) ones[j] = (bf16_t)1.0f;

    uint4 kr0, kr1, vr0, vr1;

    for (int ph = 0; ph < 2; ++ph) {
        const int qt  = ph ? (63 - p) : p;
        const int nkt = qt + 1;

        const int qglob = qt * 64 + w * 16 + l16;
        const bf16_t* qp = Qg + ((size_t)bh * 4096 + qglob) * 64;
        bf16x8 qf0 = *(const bf16x8*)(qp + quad * 8);
        bf16x8 qf1 = *(const bf16x8*)(qp + 32 + quad * 8);

        f32x4 o[4] = {};
        f32x4 lacc = {};
        float mrun = -1e30f;

        // preload kt = 0
        {
            const size_t kb = ((size_t)bh * 4096) * 64;
            const size_t vb = (size_t)bh * 64 * 4096;
            kr0 = *(const uint4*)(Kg + kb + (size_t)row0 * 64 + col0);
            kr1 = *(const uint4*)(Kg + kb + (size_t)row1 * 64 + col1);
            vr0 = *(const uint4*)(Vt + vb + (size_t)row0 * 4096 + col0);
            vr1 = *(const uint4*)(Vt + vb + (size_t)row1 * 4096 + col1);
        }
        __syncthreads();   // previous phase's buf readers are done

        for (int kt = 0; kt < nkt; ++kt) {
            const int cur = kt & 1;
            // stage this tile (regs -> LDS), contiguous b128
            *(uint4*)&Ks[cur][row0][col0] = kr0;
            *(uint4*)&Ks[cur][row1][col1] = kr1;
            *(uint4*)&Vs[cur][row0][col0] = vr0;
            *(uint4*)&Vs[cur][row1][col1] = vr1;
            __syncthreads();

            if (kt + 1 < nkt) {   // prefetch next tile; a full compute section covers it
                const size_t kb = ((size_t)bh * 4096 + (kt + 1) * 64) * 64;
                const size_t vb = (size_t)bh * 64 * 4096 + (kt + 1) * 64;
                kr0 = *(const uint4*)(Kg + kb + (size_t)row0 * 64 + col0);
                kr1 = *(const uint4*)(Kg + kb + (size_t)row1 * 64 + col1);
                vr0 = *(const uint4*)(Vt + vb + (size_t)row0 * 4096 + col0);
                vr1 = *(const uint4*)(Vt + vb + (size_t)row1 * 4096 + col1);
            }

            // fragments
            bf16x8 kf[4][2], vf[4][2];
            #pragma unroll
            for (int cb = 0; cb < 4; ++cb) {
                kf[cb][0] = *(const bf16x8*)&Ks[cur][cb * 16 + l16][quad * 8];
                kf[cb][1] = *(const bf16x8*)&Ks[cur][cb * 16 + l16][32 + quad * 8];
            }
            #pragma unroll
            for (int j = 0; j < 4; ++j) {
                vf[j][0] = *(const bf16x8*)&Vs[cur][j * 16 + l16][quad * 8];
                vf[j][1] = *(const bf16x8*)&Vs[cur][j * 16 + l16][32 + quad * 8];
            }

            // S^T = K * Q^T : lane holds col q = l16, rows key = cb*16 + quad*4 + r
            f32x4 sv[4] = {};
            #pragma unroll
            for (int cb = 0; cb < 4; ++cb) {
                sv[cb] = __builtin_amdgcn_mfma_f32_16x16x32_bf16(kf[cb][0], qf0, sv[cb], 0, 0, 0);
                sv[cb] = __builtin_amdgcn_mfma_f32_16x16x32_bf16(kf[cb][1], qf1, sv[cb], 0, 0, 0);
            }

            if (kt == qt) {   // causal mask on the diagonal tile
                #pragma unroll
                for (int cb = 0; cb < 4; ++cb) {
                    const int keyg = kt * 64 + cb * 16 + quad * 4;
                    #pragma unroll
                    for (int r = 0; r < 4; ++r)
                        if (keyg + r > qglob) sv[cb][r] = -1e30f;
                }
            }

            // max over 64 keys for q=l16: 15 in-reg + 2 cross-quad shfls
            float mloc = sv[0][0];
            #pragma unroll
            for (int cb = 0; cb < 4; ++cb)
                #pragma unroll
                for (int r = 0; r < 4; ++r) mloc = fmaxf(mloc, sv[cb][r]);
            mloc = fmaxf(mloc, __shfl_xor(mloc, 16));
            mloc = fmaxf(mloc, __shfl_xor(mloc, 32));
            const float mn = fmaxf(mrun, mloc);
            const float alpha = exp2f(mrun - mn);
            mrun = mn;

            // P = exp2(S^T - m), pack bf16, 4x ds_write_b64 into A-layout region
            #pragma unroll
            for (int cb = 0; cb < 4; ++cb) {
                bf16x4 pk;
                #pragma unroll
                for (int r = 0; r < 4; ++r) pk[r] = (bf16_t)exp2f(sv[cb][r] - mn);
                *(bf16x4*)&Ps[w][l16][cb * 16 + quad * 4] = pk;
            }
            // alpha in o-layout (row q = quad*4+r): 4 independent width-16 shuffles
            float alpha_o[4];
            #pragma unroll
            for (int r = 0; r < 4; ++r) alpha_o[r] = __shfl(alpha, quad * 4 + r, 16);

            bf16x8 pa0 = *(const bf16x8*)&Ps[w][l16][quad * 8];
            bf16x8 pa1 = *(const bf16x8*)&Ps[w][l16][32 + quad * 8];

            #pragma unroll
            for (int j = 0; j < 4; ++j)
                #pragma unroll
                for (int r = 0; r < 4; ++r) o[j][r] *= alpha_o[r];
            #pragma unroll
            for (int r = 0; r < 4; ++r) lacc[r] *= alpha_o[r];

            #pragma unroll
            for (int j = 0; j < 4; ++j) {
                o[j] = __builtin_amdgcn_mfma_f32_16x16x32_bf16(pa0, vf[j][0], o[j], 0, 0, 0);
                o[j] = __builtin_amdgcn_mfma_f32_16x16x32_bf16(pa1, vf[j][1], o[j], 0, 0, 0);
            }
            // row-sum l via ones-column MFMA (lands in o layout, all cols equal)
            lacc = __builtin_amdgcn_mfma_f32_16x16x32_bf16(pa0, ones, lacc, 0, 0, 0);
            lacc = __builtin_amdgcn_mfma_f32_16x16x32_bf16(pa1, ones, lacc, 0, 0, 0);
        }

        // epilogue: O as [B][N][H*64] bf16
        #pragma unroll
        for (int r = 0; r < 4; ++r) {
            float inv = 1.f / lacc[r];
            int n = qt * 64 + w * 16 + quad * 4 + r;
            #pragma unroll
            for (int j = 0; j < 4; ++j)
                Og[((size_t)(b_ * 4096 + n)) * 512 + hh * 64 + j * 16 + l16] =
                    (bf16_t)(o[j][r] * inv);
        }
    }
}

// ---------------- launch ----------------

extern "C" void kernel_launch(void* const* d_in, const int* in_sizes, int n_in,
                              void* d_out, int out_size, void* d_ws, size_t ws_size,
                              hipStream_t stream) {
    const float* x    = (const float*)d_in[0];   // [2,4096,512]
    const float* Wqkv = (const float*)d_in[1];   // [512,1536]
    const float* bqkv = (const float*)d_in[2];   // [1536]
    const float* Wout = (const float*)d_in[3];   // [512,512]
    const float* bout = (const float*)d_in[4];   // [512]
    float* out = (float*)d_out;                  // [2,4096,512] fp32

    char* ws = (char*)d_ws;
    bf16_t* xb  = (bf16_t*)(ws);                 // 8 MB (reused as Og after QKV GEMM)
    bf16_t* WqT = (bf16_t*)(ws + 8388608);       // 1.5 MB
    bf16_t* WoT = (bf16_t*)(ws + 9961472);       // 0.5 MB
    bf16_t* Qg  = (bf16_t*)(ws + 10485760);      // 8 MB (pre-scaled)
    bf16_t* Kg  = (bf16_t*)(ws + 18874368);      // 8 MB
    bf16_t* Vt  = (bf16_t*)(ws + 27262976);      // 8 MB ([bh][64][4096])

    convert_f32_bf16<<<4096, 256, 0, stream>>>(x, xb);
    transpose_convert<<<dim3(6, 512), 256, 0, stream>>>(Wqkv, WqT, 1536);
    transpose_convert<<<dim3(2, 512), 256, 0, stream>>>(Wout, WoT, 512);

    gemm_bt<0><<<dim3(12, 64), 256, 0, stream>>>(xb, WqT, bqkv, Qg, Kg, Vt, nullptr);

    attn_kernel<<<512, 256, 0, stream>>>(Qg, Kg, Vt, xb /* Og */);

    gemm_bt<1><<<dim3(4, 64), 256, 0, stream>>>(xb, WoT, bout, nullptr, nullptr, nullptr, out);
}